// Round 4
// baseline (124.520 us; speedup 1.0000x reference)
//
#include <hip/hip_runtime.h>
#include <math.h>

// N=20000, K=16, in_dim=128, out_dim=128, H1=H2=16
// Hermitian-reduced spectrum: e = v*16 + u, v=0..8, u=0..15  -> NE=144
#define IN_DIM 128
#define NE 144
#define OUT_DIM 128
#define KNBR 16

__device__ __forceinline__ float2 cmul(float2 a, float2 b) {
    return make_float2(a.x * b.x - a.y * b.y, a.x * b.y + a.y * b.x);
}

__device__ __forceinline__ float2 cprod8(const float2* f) {
    float2 g0 = cmul(f[0], f[1]);
    float2 g1 = cmul(f[2], f[3]);
    float2 g2 = cmul(f[4], f[5]);
    float2 g3 = cmul(f[6], f[7]);
    return cmul(cmul(g0, g1), cmul(g2, g3));
}

// ---------------------------------------------------------------------------
// Prep A: W_fft2[d][e] = sum_rc W_aff[d][rc] * exp(-2*pi*i*(u*r+v*c)/16),
//         e = v*16+u, v<=8. Block 128 does b_aff -> b_fft2.
// ---------------------------------------------------------------------------
__global__ __launch_bounds__(256) void k_prep_wfft(
    const float* __restrict__ W_aff, const float* __restrict__ b_aff,
    float2* __restrict__ W_fft2, float2* __restrict__ b_fft2)
{
    __shared__ float twc[16], tws[16];
    const int e = threadIdx.x;
    if (e < 16) {
        float a = (float)M_PI * (float)e / 8.0f;   // 2*pi*e/16
        twc[e] = cosf(a);
        tws[e] = sinf(a);
    }
    __syncthreads();
    if (e >= NE) return;
    const int u = e & 15, v = e >> 4;
    const float* src = (blockIdx.x == 128) ? b_aff : (W_aff + blockIdx.x * 256);
    float ar = 0.f, ai = 0.f;
    for (int rc = 0; rc < 256; ++rc) {
        int m = (u * (rc >> 4) + v * (rc & 15)) & 15;
        float x = src[rc];                          // uniform -> s_load
        ar = fmaf(x, twc[m], ar);
        ai = fmaf(x, -tws[m], ai);
    }
    if (blockIdx.x == 128) b_fft2[e] = make_float2(ar, ai);
    else                   W_fft2[blockIdx.x * NE + e] = make_float2(ar, ai);
}

// ---------------------------------------------------------------------------
// Prep B: folded (IFFT2 + Re + Hermitian weight) x W_mlp:
//   Wt[e][j] = (1/256) sum_rc exp(+2*pi*i*(u*r+v*c)/16) * W_mlp[rc][j]
//   stored (A,B) = ( wt*Re(Wt), -wt*Im(Wt) ),  wt = (v==0||v==8) ? 1 : 2
// ---------------------------------------------------------------------------
__global__ __launch_bounds__(128) void k_prep_weff(
    const float* __restrict__ W_mlp, float2* __restrict__ W_eff2)
{
    __shared__ float twc[16], tws[16];
    const int j = threadIdx.x;
    const int e = blockIdx.x;            // 0..143
    const int u = e & 15, v = e >> 4;
    if (j < 16) {
        float a = (float)M_PI * (float)j / 8.0f;
        twc[j] = cosf(a);
        tws[j] = sinf(a);
    }
    __syncthreads();
    float A = 0.f, B = 0.f;
    for (int rc = 0; rc < 256; ++rc) {
        int m = (u * (rc >> 4) + v * (rc & 15)) & 15;
        float wv_ = W_mlp[rc * 128 + j];            // coalesced
        A = fmaf(wv_, twc[m], A);
        B = fmaf(wv_, tws[m], B);
    }
    const float s = ((v == 0) || (v == 8)) ? (1.0f / 256.0f) : (2.0f / 256.0f);
    W_eff2[e * 128 + j] = make_float2(A * s, -B * s);
}

// ---------------------------------------------------------------------------
// Kernel 1 v2: spectra GEMM, LDS-staged transposed feature tile.
// 16 nodes/block, 192 threads; threads 0..143 own element e.
// Inner d-loop: 1 x 8B L2 load + 4 x ds_read_b128 (broadcast) + 32 FMA.
// ---------------------------------------------------------------------------
__global__ __launch_bounds__(192) void k_spectra(
    const float* __restrict__ feat, const float2* __restrict__ W_fft2,
    const float2* __restrict__ b_fft2, float2* __restrict__ F2)
{
    __shared__ float featT[IN_DIM * 16];   // featT[d*16 + m], 8 KB
    const int t = threadIdx.x;
    const int node0 = blockIdx.x * 16;

    // stage: i -> (m = i&15, d4 = i>>4); float4 read coalesces per node row
    for (int i = t; i < 512; i += 192) {
        const int m = i & 15, d4 = i >> 4;
        const float4 v = *(const float4*)&feat[(node0 + m) * IN_DIM + 4 * d4];
        featT[(4 * d4 + 0) * 16 + m] = v.x;
        featT[(4 * d4 + 1) * 16 + m] = v.y;
        featT[(4 * d4 + 2) * 16 + m] = v.z;
        featT[(4 * d4 + 3) * 16 + m] = v.w;
    }
    __syncthreads();
    if (t >= NE) return;

    float2 acc[16];
#pragma unroll
    for (int m = 0; m < 16; ++m) acc[m] = make_float2(0.f, 0.f);

#pragma unroll 2
    for (int d = 0; d < IN_DIM; ++d) {
        const float2 w = W_fft2[d * NE + t];               // coalesced 8B
        const float4 fa = *(const float4*)&featT[d * 16 + 0];   // broadcast
        const float4 fb = *(const float4*)&featT[d * 16 + 4];
        const float4 fc = *(const float4*)&featT[d * 16 + 8];
        const float4 fd = *(const float4*)&featT[d * 16 + 12];
        const float fv[16] = {fa.x, fa.y, fa.z, fa.w, fb.x, fb.y, fb.z, fb.w,
                              fc.x, fc.y, fc.z, fc.w, fd.x, fd.y, fd.z, fd.w};
#pragma unroll
        for (int m = 0; m < 16; ++m) {
            acc[m].x = fmaf(fv[m], w.x, acc[m].x);
            acc[m].y = fmaf(fv[m], w.y, acc[m].y);
        }
    }

    const float2 b = b_fft2[t];
#pragma unroll
    for (int m = 0; m < 16; ++m)
        F2[(node0 + m) * NE + t] = make_float2(acc[m].x + b.x, acc[m].y + b.y);
}

// ---------------------------------------------------------------------------
// Kernel 2 v3: gather + complex product + folded MLP. 8 nodes/block, 256 thr.
// Wave w owns e-slice [36w, 36w+36) for ALL 8 nodes:
//   product: lanes 0..35 gather+multiply (P stays in registers),
//   MLP: P broadcast via v_readlane; partials reduced across waves in LDS.
// No P_lds, one __syncthreads -> higher occupancy for latency hiding.
// ---------------------------------------------------------------------------
__global__ __launch_bounds__(256) void k_gather_mlp(
    const int* __restrict__ nbr, const float2* __restrict__ F2,
    const float2* __restrict__ W_eff2, const float* __restrict__ b_mlp,
    float* __restrict__ out)
{
    const int node0 = blockIdx.x * 8;
    const int tid  = threadIdx.x;
    const int lane = tid & 63;
    const int w    = __builtin_amdgcn_readfirstlane(tid >> 6);

    __shared__ float part[4][8][128];    // 16 KB

    // ---- product phase: lanes 0..35, e = 36w + lane, all 8 nodes
    float pr[8], pi[8];
    if (lane < 36) {
        const int e = w * 36 + lane;
#pragma unroll
        for (int m = 0; m < 8; ++m) {
            const int* nrow = nbr + (node0 + m) * KNBR;  // uniform -> s_load
            float2 f[8];
#pragma unroll
            for (int k = 0; k < 8; ++k) f[k] = F2[nrow[k] * NE + e];
            const float2 q0 = cprod8(f);
#pragma unroll
            for (int k = 0; k < 8; ++k) f[k] = F2[nrow[k + 8] * NE + e];
            const float2 q1 = cprod8(f);
            const float2 p = cmul(q0, q1);
            pr[m] = p.x;
            pi[m] = p.y;
        }
    }

    // ---- MLP phase: all 64 lanes; e-slice [36w, 36w+36)
    float acc0[8], acc1[8];
#pragma unroll
    for (int m = 0; m < 8; ++m) { acc0[m] = 0.f; acc1[m] = 0.f; }

    const int e0 = w * 36;
#pragma unroll 4
    for (int le = 0; le < 36; ++le) {
        const float2 w0 = W_eff2[(e0 + le) * 128 + lane];
        const float2 w1 = W_eff2[(e0 + le) * 128 + 64 + lane];
#pragma unroll
        for (int m = 0; m < 8; ++m) {
            const float sre = __int_as_float(
                __builtin_amdgcn_readlane(__float_as_int(pr[m]), le));
            const float sim = __int_as_float(
                __builtin_amdgcn_readlane(__float_as_int(pi[m]), le));
            acc0[m] = fmaf(sre, w0.x, fmaf(sim, w0.y, acc0[m]));
            acc1[m] = fmaf(sre, w1.x, fmaf(sim, w1.y, acc1[m]));
        }
    }

#pragma unroll
    for (int m = 0; m < 8; ++m) {
        part[w][m][lane]      = acc0[m];
        part[w][m][lane + 64] = acc1[m];
    }
    __syncthreads();

    // ---- cross-wave reduction: 1024 outputs, 4 per thread
    {
        const int m = tid >> 5;
        const int j = (tid & 31) * 4;
        float4 s = *(const float4*)&b_mlp[j];
#pragma unroll
        for (int w4 = 0; w4 < 4; ++w4) {
            const float4 p = *(const float4*)&part[w4][m][j];
            s.x += p.x; s.y += p.y; s.z += p.z; s.w += p.w;
        }
        *(float4*)&out[(node0 + m) * OUT_DIM + j] = s;
    }
}

extern "C" void kernel_launch(void* const* d_in, const int* in_sizes, int n_in,
                              void* d_out, int out_size, void* d_ws, size_t ws_size,
                              hipStream_t stream) {
    const float* feature   = (const float*)d_in[0];
    const int*   neighbors = (const int*)d_in[1];
    const float* W_aff     = (const float*)d_in[2];
    const float* b_aff     = (const float*)d_in[3];
    const float* W_mlp     = (const float*)d_in[4];
    const float* b_mlp     = (const float*)d_in[5];
    float*       out       = (float*)d_out;

    const int N = in_sizes[0] / IN_DIM;   // 20000

    float2* W_fft2 = (float2*)d_ws;            // 128*144
    float2* b_fft2 = W_fft2 + 128 * NE;        // 144
    float2* W_eff2 = b_fft2 + NE;              // 144*128
    float2* F2     = W_eff2 + NE * 128;        // N*144  (~23 MB)

    k_prep_wfft<<<129, 256, 0, stream>>>(W_aff, b_aff, W_fft2, b_fft2);
    k_prep_weff<<<NE, 128, 0, stream>>>(W_mlp, W_eff2);
    k_spectra<<<N / 16, 192, 0, stream>>>(feature, W_fft2, b_fft2, F2);
    k_gather_mlp<<<N / 8, 256, 0, stream>>>(neighbors, F2, W_eff2, b_mlp, out);
}

// Round 5
// 106.432 us; speedup vs baseline: 1.1700x; 1.1700x over previous
//
#include <hip/hip_runtime.h>
#include <hip/hip_fp16.h>
#include <math.h>

// N=20000, K=16, in_dim=128, out_dim=128, H1=H2=16
// Hermitian-reduced spectrum: e = v*16 + u, v=0..8, u=0..15  -> NE=144
#define IN_DIM 128
#define NE 144
#define OUT_DIM 128
#define KNBR 16

__device__ __forceinline__ float2 cmul(float2 a, float2 b) {
    return make_float2(a.x * b.x - a.y * b.y, a.x * b.y + a.y * b.x);
}

__device__ __forceinline__ float2 cprod8h(const __half2* f) {
    float2 c[8];
#pragma unroll
    for (int k = 0; k < 8; ++k) c[k] = __half22float2(f[k]);
    float2 g0 = cmul(c[0], c[1]);
    float2 g1 = cmul(c[2], c[3]);
    float2 g2 = cmul(c[4], c[5]);
    float2 g3 = cmul(c[6], c[7]);
    return cmul(cmul(g0, g1), cmul(g2, g3));
}

// ---------------------------------------------------------------------------
// Prep A: W_fft2[d][e] = sum_rc W_aff[d][rc] * exp(-2*pi*i*(u*r+v*c)/16),
//         e = v*16+u, v<=8. Block 128 does b_aff -> b_fft2.
// ---------------------------------------------------------------------------
__global__ __launch_bounds__(256) void k_prep_wfft(
    const float* __restrict__ W_aff, const float* __restrict__ b_aff,
    float2* __restrict__ W_fft2, float2* __restrict__ b_fft2)
{
    __shared__ float twc[16], tws[16];
    const int e = threadIdx.x;
    if (e < 16) {
        float a = (float)M_PI * (float)e / 8.0f;   // 2*pi*e/16
        twc[e] = cosf(a);
        tws[e] = sinf(a);
    }
    __syncthreads();
    if (e >= NE) return;
    const int u = e & 15, v = e >> 4;
    const float* src = (blockIdx.x == 128) ? b_aff : (W_aff + blockIdx.x * 256);
    float ar = 0.f, ai = 0.f;
    for (int rc = 0; rc < 256; ++rc) {
        int m = (u * (rc >> 4) + v * (rc & 15)) & 15;
        float x = src[rc];                          // uniform -> s_load
        ar = fmaf(x, twc[m], ar);
        ai = fmaf(x, -tws[m], ai);
    }
    if (blockIdx.x == 128) b_fft2[e] = make_float2(ar, ai);
    else                   W_fft2[blockIdx.x * NE + e] = make_float2(ar, ai);
}

// ---------------------------------------------------------------------------
// Prep B: folded (IFFT2 + Re + Hermitian weight) x W_mlp:
//   Wt[e][j] = (1/256) sum_rc exp(+2*pi*i*(u*r+v*c)/16) * W_mlp[rc][j]
//   stored (A,B) = ( wt*Re(Wt), -wt*Im(Wt) ),  wt = (v==0||v==8) ? 1 : 2
// ---------------------------------------------------------------------------
__global__ __launch_bounds__(128) void k_prep_weff(
    const float* __restrict__ W_mlp, float2* __restrict__ W_eff2)
{
    __shared__ float twc[16], tws[16];
    const int j = threadIdx.x;
    const int e = blockIdx.x;            // 0..143
    const int u = e & 15, v = e >> 4;
    if (j < 16) {
        float a = (float)M_PI * (float)j / 8.0f;
        twc[j] = cosf(a);
        tws[j] = sinf(a);
    }
    __syncthreads();
    float A = 0.f, B = 0.f;
    for (int rc = 0; rc < 256; ++rc) {
        int m = (u * (rc >> 4) + v * (rc & 15)) & 15;
        float wv_ = W_mlp[rc * 128 + j];            // coalesced
        A = fmaf(wv_, twc[m], A);
        B = fmaf(wv_, tws[m], B);
    }
    const float s = ((v == 0) || (v == 8)) ? (1.0f / 256.0f) : (2.0f / 256.0f);
    W_eff2[e * 128 + j] = make_float2(A * s, -B * s);
}

// ---------------------------------------------------------------------------
// Kernel 1 v3: spectra GEMM, M=4 x E=3 thread tile, fp16 output.
// 192 threads (3 waves), 16 nodes/block. Thread t: e-group g=t>>2 (E=3),
// m-group mg=t&3 (M=4). Per d: 1 ds_read_b128 (4 fv) + 3 float2 W loads
// (shared by 4 lanes -> L1 broadcast) + 24 FMA.
// ---------------------------------------------------------------------------
__global__ __launch_bounds__(192) void k_spectra(
    const float* __restrict__ feat, const float2* __restrict__ W_fft2,
    const float2* __restrict__ b_fft2, __half2* __restrict__ F2h)
{
    __shared__ float featT[IN_DIM * 16];   // featT[d*16 + m], 8 KB
    const int t = threadIdx.x;
    const int node0 = blockIdx.x * 16;

    // stage transposed feature tile (float4 per node-row chunk)
    for (int i = t; i < 512; i += 192) {
        const int m = i & 15, d4 = i >> 4;
        const float4 v = *(const float4*)&feat[(node0 + m) * IN_DIM + 4 * d4];
        featT[(4 * d4 + 0) * 16 + m] = v.x;
        featT[(4 * d4 + 1) * 16 + m] = v.y;
        featT[(4 * d4 + 2) * 16 + m] = v.z;
        featT[(4 * d4 + 3) * 16 + m] = v.w;
    }
    __syncthreads();

    const int g  = t >> 2;        // e-group 0..47
    const int mg = t & 3;         // m-group 0..3
    const int e0 = g * 3;
    const int m0 = mg * 4;

    float2 acc[3][4];
#pragma unroll
    for (int ei = 0; ei < 3; ++ei)
#pragma unroll
        for (int mi = 0; mi < 4; ++mi) acc[ei][mi] = make_float2(0.f, 0.f);

#pragma unroll 4
    for (int d = 0; d < IN_DIM; ++d) {
        const float4 fv = *(const float4*)&featT[d * 16 + m0];  // 16B LDS
        const float2 w0 = W_fft2[d * NE + e0 + 0];   // 4 lanes share addr
        const float2 w1 = W_fft2[d * NE + e0 + 1];
        const float2 w2 = W_fft2[d * NE + e0 + 2];
        const float f[4] = {fv.x, fv.y, fv.z, fv.w};
#pragma unroll
        for (int mi = 0; mi < 4; ++mi) {
            acc[0][mi].x = fmaf(f[mi], w0.x, acc[0][mi].x);
            acc[0][mi].y = fmaf(f[mi], w0.y, acc[0][mi].y);
            acc[1][mi].x = fmaf(f[mi], w1.x, acc[1][mi].x);
            acc[1][mi].y = fmaf(f[mi], w1.y, acc[1][mi].y);
            acc[2][mi].x = fmaf(f[mi], w2.x, acc[2][mi].x);
            acc[2][mi].y = fmaf(f[mi], w2.y, acc[2][mi].y);
        }
    }

#pragma unroll
    for (int ei = 0; ei < 3; ++ei) {
        const float2 b = b_fft2[e0 + ei];
#pragma unroll
        for (int mi = 0; mi < 4; ++mi) {
            F2h[(node0 + m0 + mi) * NE + e0 + ei] =
                __floats2half2_rn(acc[ei][mi].x + b.x, acc[ei][mi].y + b.y);
        }
    }
}

// ---------------------------------------------------------------------------
// Kernel 2 v4: R3 structure, fp16 spectra. 8 nodes/block, 256 threads.
// Product: wave w owns nodes {2w, 2w+1}; lane covers e = lane, lane+64,
// lane+128(<16). 4B loads. P -> LDS. MLP: wave w owns e-slice [36w,36w+36).
// ---------------------------------------------------------------------------
__global__ __launch_bounds__(256) void k_gather_mlp(
    const int* __restrict__ nbr, const __half2* __restrict__ F2h,
    const float2* __restrict__ W_eff2, const float* __restrict__ b_mlp,
    float* __restrict__ out)
{
    const int node0 = blockIdx.x * 8;
    const int tid  = threadIdx.x;
    const int lane = tid & 63;
    const int w    = __builtin_amdgcn_readfirstlane(tid >> 6);

    __shared__ float2 P_lds[8][NE];       // 9.2 KB
    __shared__ float  part[4][8][128];    // 16 KB

    // ---- product phase
#pragma unroll
    for (int mi = 0; mi < 2; ++mi) {
        const int m = 2 * w + mi;
        const int* nrow = nbr + (node0 + m) * KNBR;

        __half2 fA[8], fB[8], fA2[8], fB2[8];
        const int eA = lane, eB = lane + 64;
#pragma unroll
        for (int k = 0; k < 8; ++k) {
            const __half2* base = F2h + (size_t)nrow[k] * NE;   // s_load idx
            fA[k] = base[eA];
            fB[k] = base[eB];
        }
#pragma unroll
        for (int k = 0; k < 8; ++k) {
            const __half2* base = F2h + (size_t)nrow[k + 8] * NE;
            fA2[k] = base[eA];
            fB2[k] = base[eB];
        }
        P_lds[m][eA] = cmul(cprod8h(fA), cprod8h(fA2));
        P_lds[m][eB] = cmul(cprod8h(fB), cprod8h(fB2));

        if (lane < 16) {
            const int eC = lane + 128;
            __half2 fC[8], fC2[8];
#pragma unroll
            for (int k = 0; k < 8; ++k) {
                fC[k]  = F2h[(size_t)nrow[k] * NE + eC];
                fC2[k] = F2h[(size_t)nrow[k + 8] * NE + eC];
            }
            P_lds[m][eC] = cmul(cprod8h(fC), cprod8h(fC2));
        }
    }
    __syncthreads();

    // ---- MLP phase: wave w handles e in [36w, 36w+36)
    float acc0[8], acc1[8];
#pragma unroll
    for (int m = 0; m < 8; ++m) { acc0[m] = 0.f; acc1[m] = 0.f; }

    const int e0 = w * 36;
#pragma unroll 4
    for (int le = 0; le < 36; ++le) {
        const int e = e0 + le;                        // wave-uniform
        const float2 w0 = W_eff2[e * 128 + lane];
        const float2 w1 = W_eff2[e * 128 + 64 + lane];
#pragma unroll
        for (int m = 0; m < 8; ++m) {
            const float2 p = P_lds[m][e];             // uniform -> broadcast
            acc0[m] = fmaf(p.x, w0.x, fmaf(p.y, w0.y, acc0[m]));
            acc1[m] = fmaf(p.x, w1.x, fmaf(p.y, w1.y, acc1[m]));
        }
    }

#pragma unroll
    for (int m = 0; m < 8; ++m) {
        part[w][m][lane]      = acc0[m];
        part[w][m][lane + 64] = acc1[m];
    }
    __syncthreads();

    // ---- cross-wave reduction: 1024 outputs, 4 per thread
    {
        const int m = tid >> 5;
        const int j = (tid & 31) * 4;
        float4 s = *(const float4*)&b_mlp[j];
#pragma unroll
        for (int w4 = 0; w4 < 4; ++w4) {
            const float4 p = *(const float4*)&part[w4][m][j];
            s.x += p.x; s.y += p.y; s.z += p.z; s.w += p.w;
        }
        *(float4*)&out[(node0 + m) * OUT_DIM + j] = s;
    }
}

extern "C" void kernel_launch(void* const* d_in, const int* in_sizes, int n_in,
                              void* d_out, int out_size, void* d_ws, size_t ws_size,
                              hipStream_t stream) {
    const float* feature   = (const float*)d_in[0];
    const int*   neighbors = (const int*)d_in[1];
    const float* W_aff     = (const float*)d_in[2];
    const float* b_aff     = (const float*)d_in[3];
    const float* W_mlp     = (const float*)d_in[4];
    const float* b_mlp     = (const float*)d_in[5];
    float*       out       = (float*)d_out;

    const int N = in_sizes[0] / IN_DIM;   // 20000

    float2*  W_fft2 = (float2*)d_ws;           // 128*144
    float2*  b_fft2 = W_fft2 + 128 * NE;       // 144
    float2*  W_eff2 = b_fft2 + NE;             // 144*128
    __half2* F2h    = (__half2*)(W_eff2 + NE * 128);  // N*144 * 4B (~11.5 MB)

    k_prep_wfft<<<129, 256, 0, stream>>>(W_aff, b_aff, W_fft2, b_fft2);
    k_prep_weff<<<NE, 128, 0, stream>>>(W_mlp, W_eff2);
    k_spectra<<<N / 16, 192, 0, stream>>>(feature, W_fft2, b_fft2, F2h);
    k_gather_mlp<<<N / 8, 256, 0, stream>>>(neighbors, F2h, W_eff2, b_mlp, out);
}